// Round 13
// baseline (211.718 us; speedup 1.0000x reference)
//
#include <hip/hip_runtime.h>

typedef unsigned short ushort_t;
typedef __bf16 bf16x8 __attribute__((ext_vector_type(8)));
typedef float f32x4 __attribute__((ext_vector_type(4)));
typedef float f32x16 __attribute__((ext_vector_type(16)));
typedef unsigned int u32x2 __attribute__((ext_vector_type(2)));

#define DEVI __device__ __forceinline__

// Problem dims
constexpr int Ed = 1024;   // embed
constexpr int Hh = 16;     // heads
constexpr int Dd = 64;     // head dim
constexpr int Ss = 2048;   // seq
constexpr int Mm = 4096;   // B*S rows

constexpr int NX4 = Mm * Ed / 4;
constexpr int NW4 = Ed * Ed / 4;

DEVI ushort_t f2bf(float f) {      // RNE (cold paths only)
    union { float f; unsigned int i; } v; v.f = f;
    unsigned int r = v.i + 0x7fffu + ((v.i >> 16) & 1u);
    return (ushort_t)(r >> 16);
}
DEVI ushort_t f2bf_hi(float f) {   // truncation: compiles to *_d16_hi store, 0 VALU
    union { float f; unsigned int i; } v; v.f = f;
    return (ushort_t)(v.i >> 16);
}
DEVI unsigned int fbits(float f) {
    union { float f; unsigned int i; } v; v.f = f;
    return v.i;
}
DEVI float fast_exp2(float x) {    // raw v_exp_f32 (no ocml wrapper)
    float r;
    asm("v_exp_f32 %0, %1" : "=v"(r) : "v"(x));
    return r;
}
DEVI unsigned int pkbf(float lo, float hi) {   // trunc pack 2 f32 -> 2 bf16
    return (fbits(hi) & 0xffff0000u) | (fbits(lo) >> 16);
}
// v_permlane32_swap_b32: a[i>=32] <- b[i-32] ; b[i<32] <- a[i+32]
DEVI void plswap(unsigned int& a, unsigned int& b) {
#if __has_builtin(__builtin_amdgcn_permlane32_swap)
    u32x2 r = __builtin_amdgcn_permlane32_swap(a, b, false, false);
    a = r[0]; b = r[1];
#else
    asm volatile("v_permlane32_swap_b32 %0, %1" : "+v"(a), "+v"(b));
#endif
}

// One-shot fp32 -> bf16 conversion of x + 4 weight matrices (RNE).
__global__ __launch_bounds__(256) void cvt_all(
    const float* __restrict__ x,  const float* __restrict__ Wq,
    const float* __restrict__ Wk, const float* __restrict__ Wv,
    const float* __restrict__ Wo,
    ushort_t* __restrict__ xb,  ushort_t* __restrict__ Wqb,
    ushort_t* __restrict__ Wkb, ushort_t* __restrict__ Wvb,
    ushort_t* __restrict__ Wob)
{
    int i = blockIdx.x * 256 + threadIdx.x;
    const float* s; ushort_t* d; int off;
    if (i < NX4)                { s = x;  d = xb;  off = i; }
    else if (i < NX4 + NW4)     { s = Wq; d = Wqb; off = i - NX4; }
    else if (i < NX4 + 2 * NW4) { s = Wk; d = Wkb; off = i - NX4 - NW4; }
    else if (i < NX4 + 3 * NW4) { s = Wv; d = Wvb; off = i - NX4 - 2 * NW4; }
    else                        { s = Wo; d = Wob; off = i - NX4 - 3 * NW4; }
    float4 v = ((const float4*)s)[off];
    ushort4 o; o.x = f2bf(v.x); o.y = f2bf(v.y); o.z = f2bf(v.z); o.w = f2bf(v.w);
    ((ushort4*)d)[off] = o;
}

// async global->LDS, 16B per lane
DEVI void gld16(const void* g, void* l) {
    __builtin_amdgcn_global_load_lds(
        (__attribute__((address_space(1))) void*)(g),
        (__attribute__((address_space(3))) void*)(l), 16, 0, 0);
}

// ---------------- NT GEMM core (m97 pattern + XOR-swizzled LDS) ------------
DEVI void gemm_core(const ushort_t* __restrict__ A, const ushort_t* __restrict__ W,
                    ushort_t* As, ushort_t* Bs, int tm, int tn, int K,
                    f32x4 acc[4][4])
{
    const int tid  = threadIdx.x;
    const int w    = tid >> 6;
    const int lane = tid & 63;
    const int quad = lane >> 4;
    const int l15  = lane & 15;
    const int wy   = w >> 1, wx = w & 1;
    const int rowc = lane >> 3;                      // row within 8-row chunk
    const int col8s = (((lane & 7) ^ rowc) * 8);     // swizzled source granule
    const int swq  = l15 & 7;                        // read-swizzle row term

    for (int k0 = 0; k0 < K; k0 += 64) {
        __syncthreads();
#pragma unroll
        for (int i = 0; i < 4; ++i) {
            int chunk = w * 4 + i;
            int row = chunk * 8 + rowc;              // row&7 == rowc
            gld16(A + (size_t)(tm + row) * K + k0 + col8s, (char*)As + chunk * 1024);
            gld16(W + (size_t)(tn + row) * K + k0 + col8s, (char*)Bs + chunk * 1024);
        }
        __syncthreads();
#pragma unroll
        for (int ks = 0; ks < 64; ks += 32) {
            const int k4 = ks >> 3;                  // 0 or 4
            bf16x8 a[4], b[4];
#pragma unroll
            for (int mi = 0; mi < 4; ++mi)
                a[mi] = *(const bf16x8*)&As[(wy * 64 + mi * 16 + l15) * 64
                                            + (((quad + k4) ^ swq) * 8)];
#pragma unroll
            for (int ni = 0; ni < 4; ++ni)
                b[ni] = *(const bf16x8*)&Bs[(wx * 64 + ni * 16 + l15) * 64
                                            + (((quad + k4) ^ swq) * 8)];
#pragma unroll
            for (int mi = 0; mi < 4; ++mi)
#pragma unroll
                for (int ni = 0; ni < 4; ++ni)
                    acc[mi][ni] = __builtin_amdgcn_mfma_f32_16x16x32_bf16(
                        a[mi], b[ni], acc[mi][ni], 0, 0, 0);
        }
    }
}

// Fused QKV projection. Q,K stored [B,H,S,D]; V stored [B,H,D,S].
// Q epilogue pre-scales by sigmoid(z[h])*0.125*log2e -> attn p = exp2(S).
__global__ __launch_bounds__(256, 3) void qkv_gemm(
    const ushort_t* __restrict__ x,
    const ushort_t* __restrict__ Wq, const float* __restrict__ bq,
    const ushort_t* __restrict__ Wk, const float* __restrict__ bk,
    const ushort_t* __restrict__ Wv, const float* __restrict__ bv,
    const float* __restrict__ z,
    ushort_t* __restrict__ qo, ushort_t* __restrict__ ko, ushort_t* __restrict__ vto)
{
    __shared__ __align__(16) ushort_t As[128 * 64];
    __shared__ __align__(16) ushort_t Bs[128 * 64];
    const ushort_t* W; const float* bias; ushort_t* outp; int vmode;
    if (blockIdx.z == 0)      { W = Wq; bias = bq; outp = qo;  vmode = 0; }
    else if (blockIdx.z == 1) { W = Wk; bias = bk; outp = ko;  vmode = 0; }
    else                      { W = Wv; bias = bv; outp = vto; vmode = 1; }

    const int tm = blockIdx.x * 128, tn = blockIdx.y * 128;
    f32x4 acc[4][4] = {};
    gemm_core(x, W, As, Bs, tm, tn, Ed, acc);

    const int tid = threadIdx.x, w = tid >> 6, lane = tid & 63;
    const int quad = lane >> 4, l15 = lane & 15;
    const int wy = w >> 1, wx = w & 1;
    if (vmode == 0) {
#pragma unroll
        for (int ni = 0; ni < 4; ++ni) {
            int gc = tn + wx * 64 + ni * 16 + l15;
            float bb = bias[gc];
            int h = gc >> 6, d = gc & 63;
            float sc = 1.f;
            if (blockIdx.z == 0)   // Q: fold softmax scale (gate/sqrt(D)*log2e)
                sc = (1.f / (1.f + __expf(-z[h]))) * 0.18033688f;
#pragma unroll
            for (int mi = 0; mi < 4; ++mi) {
#pragma unroll
                for (int r = 0; r < 4; ++r) {
                    int gr = tm + wy * 64 + mi * 16 + quad * 4 + r;
                    int b_ = gr >> 11, s_ = gr & 2047;
                    float v = (acc[mi][ni][r] + bb) * sc;
                    outp[((size_t)(b_ * Hh + h) * Ss + s_) * Dd + d] = f2bf_hi(v);
                }
            }
        }
    } else {
#pragma unroll
        for (int ni = 0; ni < 4; ++ni) {
            int gc = tn + wx * 64 + ni * 16 + l15;
            float bb = bias[gc];
            int h = gc >> 6, d = gc & 63;
#pragma unroll
            for (int mi = 0; mi < 4; ++mi) {
                int gr0 = tm + wy * 64 + mi * 16 + quad * 4;   // r=0; same batch for r=0..3
                int b_ = gr0 >> 11, s0 = gr0 & 2047;
                u32x2 pk;
                pk[0] = pkbf(acc[mi][ni][0] + bb, acc[mi][ni][1] + bb);
                pk[1] = pkbf(acc[mi][ni][2] + bb, acc[mi][ni][3] + bb);
                *(u32x2*)&outp[((size_t)(b_ * Hh + h) * Dd + d) * Ss + s0] = pk;
            }
        }
    }
}

// Output projection: out = ctx @ Wo^T + bo, [M,E] FP32. Penalty fused in block (0,0).
__global__ __launch_bounds__(256, 3) void out_gemm(
    const ushort_t* __restrict__ ctx, const ushort_t* __restrict__ Wo,
    const float* __restrict__ bo, const float* __restrict__ z,
    float* __restrict__ out)
{
    __shared__ __align__(16) ushort_t As[128 * 64];
    __shared__ __align__(16) ushort_t Bs[64 * 64];
    const int tm = blockIdx.x * 128, tn = blockIdx.y * 64;

    const int tid  = threadIdx.x;
    const int w    = tid >> 6;
    const int lane = tid & 63;
    const int quad = lane >> 4;
    const int l15  = lane & 15;
    const int wy   = w >> 1, wx = w & 1;
    const int rowc = lane >> 3;
    const int col8s = (((lane & 7) ^ rowc) * 8);
    const int swq  = l15 & 7;

    f32x4 acc[4][2] = {};
    for (int k0 = 0; k0 < Ed; k0 += 64) {
        __syncthreads();
#pragma unroll
        for (int i = 0; i < 4; ++i) {
            int chunk = w * 4 + i;
            int row = chunk * 8 + rowc;
            gld16(ctx + (size_t)(tm + row) * Ed + k0 + col8s, (char*)As + chunk * 1024);
        }
#pragma unroll
        for (int i = 0; i < 2; ++i) {
            int chunk = w * 2 + i;
            int row = chunk * 8 + rowc;
            gld16(Wo + (size_t)(tn + row) * Ed + k0 + col8s, (char*)Bs + chunk * 1024);
        }
        __syncthreads();
#pragma unroll
        for (int ks = 0; ks < 64; ks += 32) {
            const int k4 = ks >> 3;
            bf16x8 a[4], b[2];
#pragma unroll
            for (int mi = 0; mi < 4; ++mi)
                a[mi] = *(const bf16x8*)&As[(wy * 64 + mi * 16 + l15) * 64
                                            + (((quad + k4) ^ swq) * 8)];
#pragma unroll
            for (int ni = 0; ni < 2; ++ni)
                b[ni] = *(const bf16x8*)&Bs[(wx * 32 + ni * 16 + l15) * 64
                                            + (((quad + k4) ^ swq) * 8)];
#pragma unroll
            for (int mi = 0; mi < 4; ++mi)
#pragma unroll
                for (int ni = 0; ni < 2; ++ni)
                    acc[mi][ni] = __builtin_amdgcn_mfma_f32_16x16x32_bf16(
                        a[mi], b[ni], acc[mi][ni], 0, 0, 0);
        }
    }

#pragma unroll
    for (int ni = 0; ni < 2; ++ni) {
        int gc = tn + wx * 32 + ni * 16 + l15;
        float bb = bo[gc];
#pragma unroll
        for (int mi = 0; mi < 4; ++mi)
#pragma unroll
            for (int r = 0; r < 4; ++r) {
                int gr = tm + wy * 64 + mi * 16 + quad * 4 + r;
                out[(size_t)gr * Ed + gc] = acc[mi][ni][r] + bb;
            }
    }

    if (blockIdx.x == 0 && blockIdx.y == 0 && tid == 0) {
        float s = 0.f;
        for (int hh = 0; hh < Hh; ++hh) s += 1.f / (1.f + __expf(-z[hh]));
        out[(size_t)Mm * Ed] = s * 0.01f;
    }
}

// Flash attention v26: 32x32 swapped-QK^T, softmax fully IN-REGISTER (m214/T12).
// mfma_32x32x16(K,Q): lane(hi=lane>>5,l31) holds S^T[key=crow(r,hi)][q=l31],
// crow=(r&3)+8*(r>>2)+4*hi. PV B-operand P^T[k=hi*8+j][q] built from those regs:
// per 16-key slice h: {w0,w2}=plswap(pk(p[h8],p[h8+1]), pk(p[h8+4],p[h8+5])),
// {w1,w3}=plswap(pk(p[h8+2],p[h8+3]), pk(p[h8+6],p[h8+7])). V^T A-frags are 16B
// contiguous global loads from [B,H,D,S] (L2-local). Deletes per-kt 32 ds_write
// + 4 ds_read_b128 + 2 lgkm drains + 35KB LDS; halves MFMA instr count at +20%
// rate. K LDS dbuf + 1 barrier/kt kept (v22: LDS-K needed). lsum = per-lane
// scalar + 1 shfl at end. grid (16,32)=512 blocks, 4 waves x 32q. LDS 32KB.
__global__ __launch_bounds__(256, 3) void attn(
    const ushort_t* __restrict__ Q, const ushort_t* __restrict__ Kk,
    const ushort_t* __restrict__ Vt, const float* __restrict__ z,
    ushort_t* __restrict__ ctx)
{
    __shared__ __align__(16) ushort_t Ks[2][128 * 64];   // swizzled [key][d], dbuf 32KB

    const int tid = threadIdx.x, w = tid >> 6, lane = tid & 63;
    const int hi = lane >> 5, l31 = lane & 31;
    const int lin = blockIdx.x + 16 * blockIdx.y;   // 0..511
    const int qt = lin >> 5;                        // 0..15 (128-row q tile)
    const int bh = (lin & 7) * 4 + ((lin >> 3) & 3);// XCD-local heads
    const int h = bh & (Hh - 1), b_ = bh >> 4;
    const size_t base = (size_t)bh * Ss * Dd;

    // Q fragments (B-operand): Q[q=q0+l31][d = i*16 + hi*8 .. +8], pre-scaled
    const int q0 = qt * 128 + w * 32;
    bf16x8 aQ[4];
#pragma unroll
    for (int i = 0; i < 4; ++i)
        aQ[i] = *(const bf16x8*)&Q[base + (size_t)(q0 + l31) * Dd + i * 16 + hi * 8];

    // K staging: wave w stages rows w*32..+31 (4 chunks of 8 rows)
    const int rowc = lane >> 3;
    const int gs   = ((lane & 7) ^ rowc) * 8;
    const ushort_t* kSrc[4];
#pragma unroll
    for (int i = 0; i < 4; ++i)
        kSrc[i] = Kk + base + (size_t)(w * 32 + i * 8 + rowc) * Dd + gs;
    // V^T A-operand base: row d = dblk*32 + l31, key offset hi*8
    const ushort_t* vBase = Vt + base + (size_t)l31 * Ss + hi * 8;

    f32x16 accO[2] = {};      // accO[dblk][r] = O^T[d=dblk*32+crow(r,hi)][q=l31]
    float lsum = 0.f;

    const int swq = l31 & 7;  // read-swizzle (row&7 == l31&7 since tile rows 32-aligned)

    // prologue: stage K-tile 0 (128 keys) into Ks[0]
#pragma unroll
    for (int i = 0; i < 4; ++i)
        gld16(kSrc[i], (char*)Ks[0] + (w * 4 + i) * 1024);

    for (int kt = 0; kt < Ss / 128; ++kt) {
        const int cur = kt & 1, nxt = cur ^ 1;
        __syncthreads();   // K(kt) visible; all waves done with Ks[nxt] of kt-1

        if (kt + 1 < Ss / 128) {   // prefetch K(kt+1) into Ks[nxt]
#pragma unroll
            for (int i = 0; i < 4; ++i)
                gld16(kSrc[i] + (size_t)(kt + 1) * 128 * Dd,
                      (char*)Ks[nxt] + (w * 4 + i) * 1024);
        }

#pragma unroll
        for (int sub = 0; sub < 2; ++sub) {
            // ---- QK^T: two 32-key tiles, S^T in registers ----
            f32x16 sT[2] = {};
            __builtin_amdgcn_s_setprio(1);
#pragma unroll
            for (int tt = 0; tt < 2; ++tt) {
                const int T = sub * 2 + tt;
#pragma unroll
                for (int i = 0; i < 4; ++i) {
                    bf16x8 kf = *(const bf16x8*)&Ks[cur][(T * 32 + l31) * 64
                                    + (((2 * i + hi) ^ swq) * 8)];
                    sT[tt] = __builtin_amdgcn_mfma_f32_32x32x16_bf16(kf, aQ[i], sT[tt], 0, 0, 0);
                }
            }
            __builtin_amdgcn_s_setprio(0);

            // ---- softmax in-register (Q pre-scaled: p = exp2(s)) ----
            float p[2][16];
#pragma unroll
            for (int tt = 0; tt < 2; ++tt)
#pragma unroll
                for (int r = 0; r < 16; ++r) {
                    p[tt][r] = fast_exp2(sT[tt][r]);
                    lsum += p[tt][r];
                }

            // ---- PV: 4 16-key slices, P^T via pack+permlane32_swap ----
            const int keyb = kt * 128 + sub * 64;
#pragma unroll
            for (int ks = 0; ks < 4; ++ks) {
                const int tt = ks >> 1, h8 = (ks & 1) * 8;
                unsigned int w0 = pkbf(p[tt][h8 + 0], p[tt][h8 + 1]);
                unsigned int w2 = pkbf(p[tt][h8 + 4], p[tt][h8 + 5]);
                plswap(w0, w2);
                unsigned int w1 = pkbf(p[tt][h8 + 2], p[tt][h8 + 3]);
                unsigned int w3 = pkbf(p[tt][h8 + 6], p[tt][h8 + 7]);
                plswap(w1, w3);
                union { unsigned int u[4]; bf16x8 v; } pb;
                pb.u[0] = w0; pb.u[1] = w1; pb.u[2] = w2; pb.u[3] = w3;

                __builtin_amdgcn_s_setprio(1);
#pragma unroll
                for (int dblk = 0; dblk < 2; ++dblk) {
                    bf16x8 vf = *(const bf16x8*)(vBase + (size_t)(dblk * 32) * Ss
                                                 + keyb + ks * 16);
                    accO[dblk] = __builtin_amdgcn_mfma_f32_32x32x16_bf16(vf, pb.v, accO[dblk], 0, 0, 0);
                }
                __builtin_amdgcn_s_setprio(0);
            }
        }
    }

    // lanes l and l+32 hold complementary key sets for the same q
    lsum += __shfl_xor(lsum, 32);
    const float inv = 1.f / lsum;

    // epilogue: lane owns q = q0+l31; d = dblk*32 + crow(r,hi), even-r pairs -> 4B stores
    ushort_t* crow_p = ctx + ((size_t)(b_ * Ss + q0 + l31)) * Ed + h * Dd;
#pragma unroll
    for (int dblk = 0; dblk < 2; ++dblk)
#pragma unroll
        for (int r = 0; r < 16; r += 2) {
            int d = dblk * 32 + (r & 3) + 8 * (r >> 2) + 4 * hi;
            *(unsigned int*)&crow_p[d] = pkbf(accO[dblk][r] * inv, accO[dblk][r + 1] * inv);
        }
}

extern "C" void kernel_launch(void* const* d_in, const int* in_sizes, int n_in,
                              void* d_out, int out_size, void* d_ws, size_t ws_size,
                              hipStream_t stream) {
    const float* x  = (const float*)d_in[0];
    const float* Wq = (const float*)d_in[1];
    const float* bq = (const float*)d_in[2];
    const float* Wk = (const float*)d_in[3];
    const float* bk = (const float*)d_in[4];
    const float* Wv = (const float*)d_in[5];
    const float* bv = (const float*)d_in[6];
    const float* Wo = (const float*)d_in[7];
    const float* bo = (const float*)d_in[8];
    const float* z  = (const float*)d_in[9];
    float* out = (float*)d_out;

    ushort_t* xb  = (ushort_t*)d_ws;              // [M,E]     8 MB
    ushort_t* Wqb = xb  + (size_t)Mm * Ed;        // [E,E]     2 MB
    ushort_t* Wkb = Wqb + (size_t)Ed * Ed;
    ushort_t* Wvb = Wkb + (size_t)Ed * Ed;
    ushort_t* Wob = Wvb + (size_t)Ed * Ed;
    ushort_t* qw  = Wob + (size_t)Ed * Ed;        // [B,H,S,D] 8 MB (Q pre-scaled)
    ushort_t* kw  = qw + (size_t)Mm * Ed;         // [B,H,S,D] 8 MB
    ushort_t* vT  = kw + (size_t)Mm * Ed;         // [B,H,D,S] 8 MB
    ushort_t* cx  = vT + (size_t)Mm * Ed;         // [B,S,E]   8 MB

    cvt_all<<<dim3((NX4 + 4 * NW4) / 256), dim3(256), 0, stream>>>(
        x, Wq, Wk, Wv, Wo, xb, Wqb, Wkb, Wvb, Wob);
    qkv_gemm<<<dim3(Mm / 128, Ed / 128, 3), dim3(256), 0, stream>>>(
        xb, Wqb, bq, Wkb, bk, Wvb, bv, z, qw, kw, vT);
    attn<<<dim3(Ss / 128, 2 * Hh), dim3(256), 0, stream>>>(qw, kw, vT, z, cx);
    out_gemm<<<dim3(Mm / 128, Ed / 64), dim3(256), 0, stream>>>(cx, Wob, bo, z, out);
}